// Round 15
// baseline (60.782 us; speedup 1.0000x reference)
//
#include <hip/hip_runtime.h>

#define BB 8
#define NN 128
#define CC 32

typedef short bf16x8 __attribute__((ext_vector_type(8)));
typedef float f32x4  __attribute__((ext_vector_type(4)));

static __device__ __forceinline__ unsigned f2bf(float f) {
  union { float f; unsigned u; } v; v.f = f;
  unsigned r = v.u + 0x7FFFu + ((v.u >> 16) & 1u);   // RNE
  return r >> 16;
}

struct Params {
  const float* __restrict__ atom0; const float* __restrict__ atom1; const float* __restrict__ atom2;
  const float* __restrict__ edge0; const float* __restrict__ edge1; const float* __restrict__ edge2;
  const void*  mask;
  const float* __restrict__ cg[14];
  const float* __restrict__ w0; const float* __restrict__ w1; const float* __restrict__ w2;
  float* __restrict__ out;
};

// Block = (b,i), 512 threads = 8 waves. Aggregation via MFMA (16x16x32 bf16):
// per channel c, O[x][y] = sum_j a[j][c][x]*wt[j] * e[j][c][y]
// LDS A-tile per channel: rows x<9 of [16][32k] bf16, stride 640B (=5*128,
// 128-aligned so channel-base bits 4-6 are 0 and the XOR swizzle cannot cross
// channel bases; max swizzled written offset 639 < 640). B tiles @ +20480B.
// Fragment rows >=9 read garbage -> feeds only discarded D rows/cols (each D
// element is an independent dot). XOR swizzle byte ^= ((x^c)&7)<<4 (16B-block
// preserving, identical for write and read).
// A-frag: lane l = row (l&15), k-group (l>>4)*8. C/D (m89): col=lane&15,
// row=(lane>>4)*4+reg.
__global__ __launch_bounds__(512, 2) void lgn_fused(Params p) {
  const int tid  = threadIdx.x;
  const int c    = tid & 31;
  const int s    = tid >> 5;     // 0..15
  const int lane = tid & 63;
  const int wv   = tid >> 6;     // wave 0..7
  const int blk  = blockIdx.x;
  const int b    = blk & 7;      // XCD-friendly
  const int i    = blk >> 3;

  // arena: main loop = A tiles @0 (20480B) + B tiles @20480 (+512B stray-read
  // tail pad); epilogue reuse f32: O flat 0..2591 | cat (l0@2592, l1[k][4]@2816,
  // l2[k][8]@4224) | mix 7552..9855
  __shared__ float arena[10368];
  __shared__ float sm_cg[540];
  __shared__ float sm_ai[288];
  __shared__ int   sm_list[128];
  __shared__ int   sm_nact, sm_mode;
  char* smb = (char*)arena;

  // ---- probe mask dtype ----
  if (tid == 0) sm_mode = 0;
  __syncthreads();
  if (tid < 64) {
    unsigned v = ((const unsigned*)p.mask)[tid];
    if (v == 0x3F800000u) atomicOr(&sm_mode, 2);   // float32
    else if (v > 1u)      atomicOr(&sm_mode, 1);   // packed bytes
  }
  // ---- stage cg + node-i atoms ----
  {
    constexpr int CGSZ[14] = {1,9,25, 9,9,27,45,45, 25,45,75,25,75,125};
    constexpr int CGOF[14] = {0,1,10, 35,44,53,80,125, 170,195,240,315,340,415};
    #pragma unroll
    for (int t = 0; t < 14; ++t)
      for (int idx = tid; idx < CGSZ[t]; idx += 512)
        sm_cg[CGOF[t] + idx] = p.cg[t][idx];
    const int nodeBase = (b * NN + i) * CC;
    for (int s2 = tid; s2 < 288; s2 += 512) {
      int cc = s2 / 9, comp = s2 - cc * 9;
      float v;
      if (comp == 0)      v = p.atom0[nodeBase + cc];
      else if (comp < 4)  v = p.atom1[(nodeBase + cc) * 3 + comp - 1];
      else                v = p.atom2[(nodeBase + cc) * 5 + comp - 4];
      sm_ai[s2] = v;
    }
  }
  __syncthreads();
  const int mode = (sm_mode & 2) ? 2 : sm_mode;

  // ---- ballot compaction of 128-j mask row (wave 0) ----
  if (tid < 64) {
    const int row = (b * NN + i) * NN;
    bool mv0, mv1;
    if (mode == 0) {
      mv0 = ((const int*)p.mask)[row + tid] != 0;
      mv1 = ((const int*)p.mask)[row + tid + 64] != 0;
    } else if (mode == 2) {
      mv0 = ((const float*)p.mask)[row + tid] != 0.f;
      mv1 = ((const float*)p.mask)[row + tid + 64] != 0.f;
    } else {
      mv0 = ((const unsigned char*)p.mask)[row + tid] != 0;
      mv1 = ((const unsigned char*)p.mask)[row + tid + 64] != 0;
    }
    unsigned long long b0 = __ballot(mv0);
    unsigned long long b1 = __ballot(mv1);
    int n0 = (int)__popcll(b0);
    unsigned long long lt = (1ull << tid) - 1ull;
    if (mv0) sm_list[__popcll(b0 & lt)] = tid;
    if (mv1) sm_list[n0 + __popcll(b1 & lt)] = tid + 64;
    if (tid == 0) sm_nact = n0 + (int)__popcll(b1);
  }
  __syncthreads();
  const int nact = sm_nact;
  const int nch  = (nact + 31) >> 5;   // chunks of 32 j
  if (tid < 64) {
    const int j0 = (nact > 0) ? sm_list[0] : 0;
    if (tid      >= nact) sm_list[tid]      = j0;
    if (tid + 64 >= nact) sm_list[tid + 64] = j0;
  }
  __syncthreads();

  // ---- main loop: stage chunk (bf16 [x][k] tiles) -> MFMA consume ----
  const long en0 = (long)(b * NN + i) * NN * CC;   // e0 element base
  const long an0 = (long)b * NN * CC;              // a0 element base

  f32x4 acc[4];
  #pragma unroll
  for (int q = 0; q < 4; ++q) acc[q] = (f32x4){0.f, 0.f, 0.f, 0.f};

  const int cbase = wv * 4;
  const int xr    = lane & 15;          // fragment row (A) / col (B)
  const int g16   = (lane >> 4) * 16;   // k-group byte offset (8 bf16)

  for (int ch = 0; ch < nch; ++ch) {
    // ---------- stage: 2 slots per thread; 18 swizzled b16 writes each ----------
    #pragma unroll
    for (int half = 0; half < 2; ++half) {
      const int sl = ch * 32 + s + half * 16;
      const int jg = sm_list[sl];
      const float wt = (sl < nact) ? 1.f : 0.f;
      float A[9], E[9];
      {
        const long a1b = an0 * 3 + (long)jg * 96 + c * 3;
        const long a2b = an0 * 5 + (long)jg * 160 + c * 5;
        A[0] = p.atom0[an0 + (long)jg * 32 + c];
        A[1] = p.atom1[a1b + 0]; A[2] = p.atom1[a1b + 1]; A[3] = p.atom1[a1b + 2];
        A[4] = p.atom2[a2b + 0]; A[5] = p.atom2[a2b + 1]; A[6] = p.atom2[a2b + 2];
        A[7] = p.atom2[a2b + 3]; A[8] = p.atom2[a2b + 4];
        const long e1b = en0 * 3 + (long)jg * 96 + c * 3;
        const long e2b = en0 * 5 + (long)jg * 160 + c * 5;
        E[0] = p.edge0[en0 + (long)jg * 32 + c];
        E[1] = p.edge1[e1b + 0]; E[2] = p.edge1[e1b + 1]; E[3] = p.edge1[e1b + 2];
        E[4] = p.edge2[e2b + 0]; E[5] = p.edge2[e2b + 1]; E[6] = p.edge2[e2b + 2];
        E[7] = p.edge2[e2b + 3]; E[8] = p.edge2[e2b + 4];
      }
      const int kk = s + half * 16;        // k slot 0..31
      #pragma unroll
      for (int x = 0; x < 9; ++x) {
        const unsigned ba = ((unsigned)(c * 640 + x * 64 + kk * 2))
                          ^ ((unsigned)(((x ^ c) & 7) << 4));
        *(unsigned short*)(smb + ba)         = (unsigned short)f2bf(A[x] * wt);
        *(unsigned short*)(smb + 20480 + ba) = (unsigned short)f2bf(E[x]);
      }
    }
    __syncthreads();

    // ---------- consume: 4 channels x (2 b128 reads + 1 MFMA) ----------
    #pragma unroll
    for (int q = 0; q < 4; ++q) {
      const int cq = cbase + q;
      const unsigned ba = ((unsigned)(cq * 640 + xr * 64 + g16))
                        ^ ((unsigned)(((xr ^ cq) & 7) << 4));
      const bf16x8 fa = *(const bf16x8*)(smb + ba);
      const bf16x8 fb = *(const bf16x8*)(smb + 20480 + ba);
      acc[q] = __builtin_amdgcn_mfma_f32_16x16x32_bf16(fa, fb, acc[q], 0, 0, 0);
    }
    __syncthreads();
  }

  // ---- scatter O frags to arena[c*81 + x*9 + y] (f32) ----
  {
    const int ycol = lane & 15;                    // D col = y
    const int xb   = (lane >> 4) * 4;              // D row base = x
    if (ycol < 9) {
      #pragma unroll
      for (int q = 0; q < 4; ++q) {
        #pragma unroll
        for (int r = 0; r < 4; ++r) {
          const int x = xb + r;
          if (x < 9) arena[(cbase + q) * 81 + x * 9 + ycol] = acc[q][r];
        }
      }
    }
  }
  __syncthreads();

  // ---- build cat: l0 [k] @2592, l1 [k][4] @2816, l2 [k][8] @4224 ----
  {
    constexpr int colL[31]   = {0,0,0,0,0,0,0, 1,1,1,1,1,1,1,1,1,1,1, 2,2,2,2,2,2,2,2,2,2,2,2,2};
    constexpr int colKind[31]= {0,0,0,1,2,2,2, 0,0,0,0,0,1,2,2,2,2,2, 0,0,0,0,0,0,1,2,2,2,2,2,2};
    constexpr int colL1[31]  = {0,1,2,0,0,1,2, 0,1,1,1,2,0,0,1,1,1,2, 0,1,1,2,2,2,0,0,1,1,2,2,2};
    constexpr int colL2[31]  = {0,1,2,0,0,1,2, 1,0,1,2,1,0,1,0,1,2,1, 2,1,2,0,1,2,0,2,1,2,0,1,2};
    constexpr int colCg[31]  = {0,1,10,0,0,1,10, 35,44,53,80,125,0,35,44,53,80,125,
                                170,195,240,315,340,415,0,170,195,240,315,340,415};
    constexpr int colP[31]   = {0,1,2,3,4,5,6, 0,1,2,3,4,5,6,7,8,9,10, 0,1,2,3,4,5,6,7,8,9,10,11,12};
    constexpr int DD[3]      = {1,3,5};
    constexpr int catBase[3] = {2592, 2816, 4224};
    constexpr int catStr[3]  = {1, 4, 8};
    constexpr int aOff[3]    = {0,1,4};

    for (int col = s; col < 31; col += 16) {
      const int l = colL[col];
      const int d = DD[l];
      const int knd = colKind[col];
      float* catp = &arena[catBase[l] + (colP[col] * CC + c) * catStr[l]];
      if (knd == 1) {             // identity
        for (int z = 0; z < d; ++z) catp[z] = sm_ai[c * 9 + aOff[l] + z];
      } else if (knd == 0) {      // aggregate: contract O(flat x*9+y) with cg
        const int l1 = colL1[col], l2 = colL2[col];
        const int d1 = DD[l1], d2 = DD[l2];
        const int x0 = aOff[l1], y0 = aOff[l2];
        const float* cgp = &sm_cg[colCg[col]];
        const float* Ofl = &arena[c * 81];
        for (int z = 0; z < d; ++z) {
          float sum = 0.f;
          for (int xi = 0; xi < d1; ++xi)
            for (int yi = 0; yi < d2; ++yi)
              sum += Ofl[(x0 + xi) * 9 + y0 + yi] * cgp[(xi * d2 + yi) * d + z];
          catp[z] = sum;
        }
      } else {                    // power: atom_i x atom_i
        const int l1 = colL1[col], l2 = colL2[col];
        const int d1 = DD[l1], d2 = DD[l2];
        const float* cgp = &sm_cg[colCg[col]];
        const float* a1p = &sm_ai[c * 9 + aOff[l1]];
        const float* a2p = &sm_ai[c * 9 + aOff[l2]];
        for (int z = 0; z < d; ++z) {
          float sum = 0.f;
          for (int xi = 0; xi < d1; ++xi)
            for (int yi = 0; yi < d2; ++yi)
              sum += a1p[xi] * a2p[yi] * cgp[(xi * d2 + yi) * d + z];
          catp[z] = sum;
        }
      }
    }
  }
  __syncthreads();

  // ---- channel mix (16-way k-split, wide LDS reads, shfl pair-combine) ----
  {
    float accm[9];
    #pragma unroll
    for (int q = 0; q < 9; ++q) accm[q] = 0.f;
    const int co = c;
    #pragma unroll
    for (int k0 = 0; k0 < 224; k0 += 16) {
      const int k = k0 + s;
      accm[0] += arena[2592 + k] * p.w0[k * CC + co];
    }
    #pragma unroll
    for (int k0 = 0; k0 < 352; k0 += 16) {
      const int k = k0 + s;
      const float4 v = *(const float4*)&arena[2816 + k * 4];
      const float wv2 = p.w1[k * CC + co];
      accm[1] += v.x * wv2;
      accm[2] += v.y * wv2;
      accm[3] += v.z * wv2;
    }
    #pragma unroll
    for (int k0 = 0; k0 < 416; k0 += 16) {
      const int k = k0 + s;
      const float4 v = *(const float4*)&arena[4224 + k * 8];
      const float v4 = arena[4224 + k * 8 + 4];
      const float wv2 = p.w2[k * CC + co];
      accm[4] += v.x * wv2;
      accm[5] += v.y * wv2;
      accm[6] += v.z * wv2;
      accm[7] += v.w * wv2;
      accm[8] += v4  * wv2;
    }
    #pragma unroll
    for (int q = 0; q < 9; ++q) accm[q] += __shfl_down(accm[q], 32);
    if ((s & 1) == 0) {
      #pragma unroll
      for (int q = 0; q < 9; ++q)
        arena[7552 + (s >> 1) * 288 + co * 9 + q] = accm[q];
    }
  }
  __syncthreads();

  // ---- final partial-sum + store ----
  if (tid < 288) {
    float v = 0.f;
    #pragma unroll
    for (int gg = 0; gg < 8; ++gg) v += arena[7552 + gg * 288 + tid];
    const int co = tid / 9, zz = tid - co * 9;
    const int nb = (b * NN + i) * CC;
    int oidx;
    if (zz == 0)     oidx = nb + co;                           // l=0
    else if (zz < 4) oidx = 32768  + (nb + co) * 3 + (zz - 1); // l=1
    else             oidx = 131072 + (nb + co) * 5 + (zz - 4); // l=2
    p.out[oidx] = v;
  }
}

extern "C" void kernel_launch(void* const* d_in, const int* in_sizes, int n_in,
                              void* d_out, int out_size, void* d_ws, size_t ws_size,
                              hipStream_t stream) {
  Params p;
  const bool interleaved = (in_sizes[1] == BB * NN * NN * CC);
  if (interleaved) {
    p.atom0 = (const float*)d_in[0]; p.edge0 = (const float*)d_in[1];
    p.atom1 = (const float*)d_in[2]; p.edge1 = (const float*)d_in[3];
    p.atom2 = (const float*)d_in[4]; p.edge2 = (const float*)d_in[5];
  } else {
    p.atom0 = (const float*)d_in[0]; p.atom1 = (const float*)d_in[1]; p.atom2 = (const float*)d_in[2];
    p.edge0 = (const float*)d_in[3]; p.edge1 = (const float*)d_in[4]; p.edge2 = (const float*)d_in[5];
  }
  p.mask = d_in[6];
  for (int t = 0; t < 14; ++t) p.cg[t] = (const float*)d_in[7 + t];
  p.w0 = (const float*)d_in[21];
  p.w1 = (const float*)d_in[22];
  p.w2 = (const float*)d_in[23];
  p.out = (float*)d_out;

  lgn_fused<<<dim3(BB * NN), dim3(512), 0, stream>>>(p);
}